// Round 1
// baseline (543.369 us; speedup 1.0000x reference)
//
#include <hip/hip_runtime.h>
#include <stdint.h>

#define NNODES 50000
#define NEDGES 800000
#define DDIM 256
#define NCLS 32
#define NGRAPH 64

typedef short bf16x8 __attribute__((ext_vector_type(8)));
typedef float f32x4 __attribute__((ext_vector_type(4)));

typedef __attribute__((address_space(1))) const char glb_c;
typedef __attribute__((address_space(3))) char lds_c;

__device__ __forceinline__ unsigned short f2b(float f) {
  uint32_t u = __builtin_bit_cast(uint32_t, f);
  u += 0x7FFFu + ((u >> 16) & 1u);
  return (unsigned short)(u >> 16);
}
__device__ __forceinline__ float b2f(unsigned short u) {
  return __builtin_bit_cast(float, (uint32_t)u << 16);
}

__device__ __forceinline__ void gload16(const void* g, const void* l) {
  __builtin_amdgcn_global_load_lds((glb_c*)g, (lds_c*)l, 16, 0, 0);
}

// ---------------- CSR build ----------------

__global__ void k_hist(const int* __restrict__ dst, int* __restrict__ cnt) {
  int e = blockIdx.x * 256 + threadIdx.x;
  if (e < NEDGES) atomicAdd(&cnt[dst[e]], 1);
}

// single block, 1024 threads. cnt aliases cursor: reads cnt[i], writes
// cursor[i] (exclusive) after the read — safe within-thread.
__global__ void k_scan(int* __restrict__ cnt, int* __restrict__ rowptr,
                       int* __restrict__ cursor) {
  __shared__ int wsum[16];
  int tid = threadIdx.x;
  int lane = tid & 63, wid = tid >> 6;
  int base = 0;
  for (int start = 0; start < NNODES; start += 1024) {
    int i = start + tid;
    int v = (i < NNODES) ? cnt[i] : 0;
    int s = v;
#pragma unroll
    for (int o = 1; o < 64; o <<= 1) {
      int t = __shfl_up(s, o, 64);
      if (lane >= o) s += t;
    }
    if (lane == 63) wsum[wid] = s;
    __syncthreads();
    if (wid == 0) {
      int w = (lane < 16) ? wsum[lane] : 0;
#pragma unroll
      for (int o = 1; o < 16; o <<= 1) {
        int t = __shfl_up(w, o, 64);
        if (lane >= o) w += t;
      }
      if (lane < 16) wsum[lane] = w;
    }
    __syncthreads();
    int wbase = (wid > 0) ? wsum[wid - 1] : 0;
    int incl = base + wbase + s;
    if (i < NNODES) {
      rowptr[i + 1] = incl;
      cursor[i] = incl - v;
    }
    base += wsum[15];
    __syncthreads();
  }
  if (tid == 0) rowptr[0] = 0;
}

__global__ void k_fill(const int* __restrict__ src, const int* __restrict__ dst,
                       int* __restrict__ cursor, int* __restrict__ col) {
  int e = blockIdx.x * 256 + threadIdx.x;
  if (e < NEDGES) {
    int p = atomicAdd(&cursor[dst[e]], 1);
    col[p] = src[e];
  }
}

// ---------------- conversions ----------------

__global__ void k_cvt_x(const float* __restrict__ x, unsigned short* __restrict__ xb) {
  int i = blockIdx.x * 256 + threadIdx.x;  // over float4s: NNODES*DDIM/4
  if (i < NNODES * DDIM / 4) {
    float4 v = ((const float4*)x)[i];
    ushort4 o;
    o.x = f2b(v.x); o.y = f2b(v.y); o.z = f2b(v.z); o.w = f2b(v.w);
    ((ushort4*)xb)[i] = o;
  }
}

// WT[layer][n][k], n in 0..255, k in 0..511; k<256 -> W_l[k][n], else W_r[k-256][n]
__global__ void k_cvt_w(const float* __restrict__ W1l, const float* __restrict__ W1r,
                        const float* __restrict__ W2l, const float* __restrict__ W2r,
                        unsigned short* __restrict__ WT1, unsigned short* __restrict__ WT2) {
  int idx = blockIdx.x * 256 + threadIdx.x;  // 2*256*512
  int which = idx >> 17;
  int id2 = idx & 131071;
  int n = id2 >> 9, k = id2 & 511;
  const float* Wl = which ? W2l : W1l;
  const float* Wr = which ? W2r : W1r;
  unsigned short* WT = which ? WT2 : WT1;
  float v = (k < 256) ? Wl[k * 256 + n] : Wr[(k - 256) * 256 + n];
  WT[id2] = f2b(v);
}

// ---------------- aggregation (wave per node, bf16 in, bf16 out) ----------------

__device__ __forceinline__ void addrow(const unsigned short* __restrict__ feat,
                                       int node, int lane,
                                       float& a0, float& a1, float& a2, float& a3) {
  const ushort4 v = *(const ushort4*)(feat + (size_t)node * DDIM + lane * 4);
  a0 += b2f(v.x); a1 += b2f(v.y); a2 += b2f(v.z); a3 += b2f(v.w);
}

__global__ void k_agg(const unsigned short* __restrict__ feat,
                      const int* __restrict__ rowptr, const int* __restrict__ col,
                      unsigned short* __restrict__ out) {
  int node = (blockIdx.x << 2) + (threadIdx.x >> 6);
  if (node >= NNODES) return;
  int lane = threadIdx.x & 63;
  int s = rowptr[node], e = rowptr[node + 1];
  float a0 = 0.f, a1 = 0.f, a2 = 0.f, a3 = 0.f;
  int i = s;
  for (; i + 4 <= e; i += 4) {
    int c0 = col[i], c1 = col[i + 1], c2 = col[i + 2], c3 = col[i + 3];
    addrow(feat, c0, lane, a0, a1, a2, a3);
    addrow(feat, c1, lane, a0, a1, a2, a3);
    addrow(feat, c2, lane, a0, a1, a2, a3);
    addrow(feat, c3, lane, a0, a1, a2, a3);
  }
  for (; i < e; ++i) addrow(feat, col[i], lane, a0, a1, a2, a3);
  float inv = (e > s) ? 1.f / (float)(e - s) : 0.f;
  ushort4 o;
  o.x = f2b(a0 * inv); o.y = f2b(a1 * inv); o.z = f2b(a2 * inv); o.w = f2b(a3 * inv);
  ((ushort4*)out)[node * (DDIM / 4) + lane] = o;
}

// ---------------- GEMM: out = relu(Aagg @ W_l + Aroot @ W_r + b), bf16 ----------------
// 128x128 tile, BK=32, 4 waves (2x2 of 64x64), global_load_lds(16B), K=512 concat.

__global__ void k_gemm(const unsigned short* __restrict__ Aagg,
                       const unsigned short* __restrict__ Aroot,
                       const unsigned short* __restrict__ WT,   // [256][512]
                       const float* __restrict__ bias,          // [256]
                       unsigned short* __restrict__ out) {      // [M][256]
  __shared__ unsigned short As[128 * 32];
  __shared__ unsigned short Bs[128 * 32];
  int m0 = blockIdx.x * 128;
  int n0 = blockIdx.y * 128;
  int tid = threadIdx.x, lane = tid & 63, wv = tid >> 6;
  int wm = wv >> 1, wn = wv & 1;

  f32x4 acc[4][4];
#pragma unroll
  for (int m = 0; m < 4; ++m)
#pragma unroll
    for (int n = 0; n < 4; ++n) acc[m][n] = (f32x4)0.f;

  for (int kt = 0; kt < 16; ++kt) {
    int k = kt * 32;
    const unsigned short* Abase = (k < 256) ? Aagg : Aroot;
    int kk = k & 255;
    // stage A (8192 B): 512 chunks of 16B; idx = q*256 + tid
#pragma unroll
    for (int q = 0; q < 2; ++q) {
      int idx = q * 256 + tid;
      int row = idx >> 2, seg = idx & 3;
      int gr = m0 + row;
      if (gr >= NNODES) gr = NNODES - 1;
      const unsigned short* sp = Abase + (size_t)gr * DDIM + kk + seg * 8;
      gload16(sp, (const char*)As + (q * 256 + wv * 64) * 16);
    }
    // stage B (8192 B): Bs[n][k'] from WT[n0+row][k + seg*8]
#pragma unroll
    for (int q = 0; q < 2; ++q) {
      int idx = q * 256 + tid;
      int row = idx >> 2, seg = idx & 3;
      const unsigned short* sp = WT + (size_t)(n0 + row) * 512 + k + seg * 8;
      gload16(sp, (const char*)Bs + (q * 256 + wv * 64) * 16);
    }
    __syncthreads();

    bf16x8 af[4], bfr[4];
    int kb = (lane >> 4) * 8;
    int rA = wm * 64 + (lane & 15);
    int rB = wn * 64 + (lane & 15);
#pragma unroll
    for (int m = 0; m < 4; ++m) af[m] = *(const bf16x8*)&As[(rA + m * 16) * 32 + kb];
#pragma unroll
    for (int n = 0; n < 4; ++n) bfr[n] = *(const bf16x8*)&Bs[(rB + n * 16) * 32 + kb];
#pragma unroll
    for (int m = 0; m < 4; ++m)
#pragma unroll
      for (int n = 0; n < 4; ++n)
        acc[m][n] = __builtin_amdgcn_mfma_f32_16x16x32_bf16(af[m], bfr[n], acc[m][n], 0, 0, 0);
    __syncthreads();
  }

  // epilogue: C/D layout col=lane&15, row=(lane>>4)*4+j
  int rbase = m0 + wm * 64 + (lane >> 4) * 4;
  int cbase = n0 + wn * 64 + (lane & 15);
#pragma unroll
  for (int n = 0; n < 4; ++n) {
    int cc = cbase + n * 16;
    float bv = bias[cc];
#pragma unroll
    for (int m = 0; m < 4; ++m) {
#pragma unroll
      for (int j = 0; j < 4; ++j) {
        int r = rbase + m * 16 + j;
        if (r < NNODES) {
          float v = acc[m][n][j] + bv;
          v = fmaxf(v, 0.f);
          out[(size_t)r * DDIM + cc] = f2b(v);
        }
      }
    }
  }
}

// ---------------- pool + classifier ----------------

__global__ void k_pool(const unsigned short* __restrict__ h2,
                       const int* __restrict__ batch,
                       const float* __restrict__ Wc, const float* __restrict__ bc,
                       float* __restrict__ out) {
  int g = blockIdx.x;
  __shared__ int sh_lo, sh_hi;
  __shared__ float colmean[DDIM];
  if (threadIdx.x == 0) {
    int lo = 0, hi = NNODES;
    while (lo < hi) { int m = (lo + hi) >> 1; if (batch[m] < g) lo = m + 1; else hi = m; }
    sh_lo = lo;
    int lo2 = lo, hi2 = NNODES;
    while (lo2 < hi2) { int m = (lo2 + hi2) >> 1; if (batch[m] < g + 1) lo2 = m + 1; else hi2 = m; }
    sh_hi = lo2;
  }
  __syncthreads();
  int lo = sh_lo, hi = sh_hi;
  int c = threadIdx.x;
  float s = 0.f;
  for (int r = lo; r < hi; ++r) s += b2f(h2[(size_t)r * DDIM + c]);
  colmean[c] = (hi > lo) ? s / (float)(hi - lo) : 0.f;
  __syncthreads();
  if (c < NCLS) {
    float o = bc[c];
#pragma unroll 4
    for (int k = 0; k < DDIM; ++k) o += colmean[k] * Wc[k * NCLS + c];
    out[g * NCLS + c] = o;
  }
}

// ---------------- launch ----------------

extern "C" void kernel_launch(void* const* d_in, const int* in_sizes, int n_in,
                              void* d_out, int out_size, void* d_ws, size_t ws_size,
                              hipStream_t stream) {
  const float* x    = (const float*)d_in[0];
  const int* eidx   = (const int*)d_in[1];
  const int* batch  = (const int*)d_in[2];
  const float* W1l  = (const float*)d_in[3];
  const float* b1   = (const float*)d_in[4];
  const float* W1r  = (const float*)d_in[5];
  const float* W2l  = (const float*)d_in[6];
  const float* b2   = (const float*)d_in[7];
  const float* W2r  = (const float*)d_in[8];
  const float* Wc   = (const float*)d_in[9];
  const float* bc   = (const float*)d_in[10];
  float* out = (float*)d_out;

  const int* esrc = eidx;
  const int* edst = eidx + NEDGES;

  char* w = (char*)d_ws;
  size_t off = 0;
  auto alloc = [&](size_t bytes) -> char* {
    char* p = w + off;
    off = (off + bytes + 255) & ~(size_t)255;
    return p;
  };
  int* rowptr = (int*)alloc((NNODES + 1) * sizeof(int));
  int* cursor = (int*)alloc(NNODES * sizeof(int));   // also the histogram buffer
  int* col    = (int*)alloc(NEDGES * sizeof(int));
  unsigned short* xb   = (unsigned short*)alloc((size_t)NNODES * DDIM * 2);  // later reused for h2
  unsigned short* h1b  = (unsigned short*)alloc((size_t)NNODES * DDIM * 2);
  unsigned short* aggb = (unsigned short*)alloc((size_t)NNODES * DDIM * 2);
  unsigned short* WT1  = (unsigned short*)alloc(512 * 256 * 2);
  unsigned short* WT2  = (unsigned short*)alloc(512 * 256 * 2);

  // CSR build
  hipMemsetAsync(cursor, 0, NNODES * sizeof(int), stream);
  k_hist<<<(NEDGES + 255) / 256, 256, 0, stream>>>(edst, cursor);
  k_scan<<<1, 1024, 0, stream>>>(cursor, rowptr, cursor);
  k_fill<<<(NEDGES + 255) / 256, 256, 0, stream>>>(esrc, edst, cursor, col);

  // conversions
  k_cvt_x<<<(NNODES * DDIM / 4 + 255) / 256, 256, 0, stream>>>(x, xb);
  k_cvt_w<<<(2 * 256 * 512 + 255) / 256, 256, 0, stream>>>(W1l, W1r, W2l, W2r, WT1, WT2);

  dim3 ggrid((NNODES + 127) / 128, 2);

  // layer 1
  k_agg<<<(NNODES + 3) / 4, 256, 0, stream>>>(xb, rowptr, col, aggb);
  k_gemm<<<ggrid, 256, 0, stream>>>(aggb, xb, WT1, b1, h1b);

  // layer 2 (h2 -> xb, reusing the buffer)
  k_agg<<<(NNODES + 3) / 4, 256, 0, stream>>>(h1b, rowptr, col, aggb);
  k_gemm<<<ggrid, 256, 0, stream>>>(aggb, h1b, WT2, b2, xb);

  // pool + classifier
  k_pool<<<NGRAPH, 256, 0, stream>>>(xb, batch, Wc, bc, out);
}

// Round 2
// 389.977 us; speedup vs baseline: 1.3933x; 1.3933x over previous
//
#include <hip/hip_runtime.h>
#include <stdint.h>

#define NNODES 50000
#define NEDGES 800000
#define DDIM 256
#define NCLS 32
#define NGRAPH 64

typedef short bf16x8 __attribute__((ext_vector_type(8)));
typedef float f32x4 __attribute__((ext_vector_type(4)));

typedef __attribute__((address_space(1))) const char glb_c;
typedef __attribute__((address_space(3))) char lds_c;

__device__ __forceinline__ unsigned short f2b(float f) {
  uint32_t u = __builtin_bit_cast(uint32_t, f);
  u += 0x7FFFu + ((u >> 16) & 1u);
  return (unsigned short)(u >> 16);
}
__device__ __forceinline__ float b2f(unsigned short u) {
  return __builtin_bit_cast(float, (uint32_t)u << 16);
}

__device__ __forceinline__ void gload16(const void* g, const void* l) {
  __builtin_amdgcn_global_load_lds((glb_c*)g, (lds_c*)l, 16, 0, 0);
}

// ---------------- CSR build ----------------

__global__ void k_hist(const int* __restrict__ dst, int* __restrict__ cnt) {
  int e = blockIdx.x * 256 + threadIdx.x;
  if (e < NEDGES) atomicAdd(&cnt[dst[e]], 1);
}

// single block, 1024 threads. cnt aliases cursor: reads cnt[i], writes
// cursor[i] (exclusive) after the read — safe within-thread.
__global__ void k_scan(int* __restrict__ cnt, int* __restrict__ rowptr,
                       int* __restrict__ cursor) {
  __shared__ int wsum[16];
  int tid = threadIdx.x;
  int lane = tid & 63, wid = tid >> 6;
  int base = 0;
  for (int start = 0; start < NNODES; start += 1024) {
    int i = start + tid;
    int v = (i < NNODES) ? cnt[i] : 0;
    int s = v;
#pragma unroll
    for (int o = 1; o < 64; o <<= 1) {
      int t = __shfl_up(s, o, 64);
      if (lane >= o) s += t;
    }
    if (lane == 63) wsum[wid] = s;
    __syncthreads();
    if (wid == 0) {
      int w = (lane < 16) ? wsum[lane] : 0;
#pragma unroll
      for (int o = 1; o < 16; o <<= 1) {
        int t = __shfl_up(w, o, 64);
        if (lane >= o) w += t;
      }
      if (lane < 16) wsum[lane] = w;
    }
    __syncthreads();
    int wbase = (wid > 0) ? wsum[wid - 1] : 0;
    int incl = base + wbase + s;
    if (i < NNODES) {
      rowptr[i + 1] = incl;
      cursor[i] = incl - v;
    }
    base += wsum[15];
    __syncthreads();
  }
  if (tid == 0) rowptr[0] = 0;
}

__global__ void k_fill(const int* __restrict__ src, const int* __restrict__ dst,
                       int* __restrict__ cursor, int* __restrict__ col) {
  int e = blockIdx.x * 256 + threadIdx.x;
  if (e < NEDGES) {
    int p = atomicAdd(&cursor[dst[e]], 1);
    col[p] = src[e];
  }
}

// ---------------- conversions ----------------

__global__ void k_cvt_x(const float* __restrict__ x, unsigned short* __restrict__ xb) {
  int i = blockIdx.x * 256 + threadIdx.x;  // over float4s: NNODES*DDIM/4
  if (i < NNODES * DDIM / 4) {
    float4 v = ((const float4*)x)[i];
    ushort4 o;
    o.x = f2b(v.x); o.y = f2b(v.y); o.z = f2b(v.z); o.w = f2b(v.w);
    ((ushort4*)xb)[i] = o;
  }
}

// WT[layer][n][k], n in 0..255, k in 0..511; k<256 -> W_l[k][n], else W_r[k-256][n]
__global__ void k_cvt_w(const float* __restrict__ W1l, const float* __restrict__ W1r,
                        const float* __restrict__ W2l, const float* __restrict__ W2r,
                        unsigned short* __restrict__ WT1, unsigned short* __restrict__ WT2) {
  int idx = blockIdx.x * 256 + threadIdx.x;  // 2*256*512
  int which = idx >> 17;
  int id2 = idx & 131071;
  int n = id2 >> 9, k = id2 & 511;
  const float* Wl = which ? W2l : W1l;
  const float* Wr = which ? W2r : W1r;
  unsigned short* WT = which ? WT2 : WT1;
  float v = (k < 256) ? Wl[k * 256 + n] : Wr[(k - 256) * 256 + n];
  WT[id2] = f2b(v);
}

// ---------------- aggregation (wave per node, bf16 in, bf16 out) ----------------

__device__ __forceinline__ void addrow(const unsigned short* __restrict__ feat,
                                       int node, int lane,
                                       float& a0, float& a1, float& a2, float& a3) {
  const ushort4 v = *(const ushort4*)(feat + (size_t)node * DDIM + lane * 4);
  a0 += b2f(v.x); a1 += b2f(v.y); a2 += b2f(v.z); a3 += b2f(v.w);
}

__global__ void k_agg(const unsigned short* __restrict__ feat,
                      const int* __restrict__ rowptr, const int* __restrict__ col,
                      unsigned short* __restrict__ out) {
  int node = (blockIdx.x << 2) + (threadIdx.x >> 6);
  if (node >= NNODES) return;
  int lane = threadIdx.x & 63;
  int s = rowptr[node], e = rowptr[node + 1];
  float a0 = 0.f, a1 = 0.f, a2 = 0.f, a3 = 0.f;
  int i = s;
  for (; i + 4 <= e; i += 4) {
    int c0 = col[i], c1 = col[i + 1], c2 = col[i + 2], c3 = col[i + 3];
    addrow(feat, c0, lane, a0, a1, a2, a3);
    addrow(feat, c1, lane, a0, a1, a2, a3);
    addrow(feat, c2, lane, a0, a1, a2, a3);
    addrow(feat, c3, lane, a0, a1, a2, a3);
  }
  for (; i < e; ++i) addrow(feat, col[i], lane, a0, a1, a2, a3);
  float inv = (e > s) ? 1.f / (float)(e - s) : 0.f;
  ushort4 o;
  o.x = f2b(a0 * inv); o.y = f2b(a1 * inv); o.z = f2b(a2 * inv); o.w = f2b(a3 * inv);
  ((ushort4*)out)[node * (DDIM / 4) + lane] = o;
}

// ---------------- GEMM: out = relu(Aagg @ W_l + Aroot @ W_r + b), bf16 ----------------
// 128x128 tile, BK=32, 4 waves (2x2 of 64x64), global_load_lds(16B), K=512 concat.

__global__ void k_gemm(const unsigned short* __restrict__ Aagg,
                       const unsigned short* __restrict__ Aroot,
                       const unsigned short* __restrict__ WT,   // [256][512]
                       const float* __restrict__ bias,          // [256]
                       unsigned short* __restrict__ out) {      // [M][256]
  __shared__ unsigned short As[128 * 32];
  __shared__ unsigned short Bs[128 * 32];
  int m0 = blockIdx.x * 128;
  int n0 = blockIdx.y * 128;
  int tid = threadIdx.x, lane = tid & 63, wv = tid >> 6;
  int wm = wv >> 1, wn = wv & 1;

  f32x4 acc[4][4];
#pragma unroll
  for (int m = 0; m < 4; ++m)
#pragma unroll
    for (int n = 0; n < 4; ++n) acc[m][n] = (f32x4)0.f;

  for (int kt = 0; kt < 16; ++kt) {
    int k = kt * 32;
    const unsigned short* Abase = (k < 256) ? Aagg : Aroot;
    int kk = k & 255;
    // stage A (8192 B): 512 chunks of 16B; idx = q*256 + tid
#pragma unroll
    for (int q = 0; q < 2; ++q) {
      int idx = q * 256 + tid;
      int row = idx >> 2, seg = idx & 3;
      int gr = m0 + row;
      if (gr >= NNODES) gr = NNODES - 1;
      const unsigned short* sp = Abase + (size_t)gr * DDIM + kk + seg * 8;
      gload16(sp, (const char*)As + (q * 256 + wv * 64) * 16);
    }
    // stage B (8192 B): Bs[n][k'] from WT[n0+row][k + seg*8]
#pragma unroll
    for (int q = 0; q < 2; ++q) {
      int idx = q * 256 + tid;
      int row = idx >> 2, seg = idx & 3;
      const unsigned short* sp = WT + (size_t)(n0 + row) * 512 + k + seg * 8;
      gload16(sp, (const char*)Bs + (q * 256 + wv * 64) * 16);
    }
    __syncthreads();

    bf16x8 af[4], bfr[4];
    int kb = (lane >> 4) * 8;
    int rA = wm * 64 + (lane & 15);
    int rB = wn * 64 + (lane & 15);
#pragma unroll
    for (int m = 0; m < 4; ++m) af[m] = *(const bf16x8*)&As[(rA + m * 16) * 32 + kb];
#pragma unroll
    for (int n = 0; n < 4; ++n) bfr[n] = *(const bf16x8*)&Bs[(rB + n * 16) * 32 + kb];
#pragma unroll
    for (int m = 0; m < 4; ++m)
#pragma unroll
      for (int n = 0; n < 4; ++n)
        acc[m][n] = __builtin_amdgcn_mfma_f32_16x16x32_bf16(af[m], bfr[n], acc[m][n], 0, 0, 0);
    __syncthreads();
  }

  // epilogue: C/D layout col=lane&15, row=(lane>>4)*4+j
  int rbase = m0 + wm * 64 + (lane >> 4) * 4;
  int cbase = n0 + wn * 64 + (lane & 15);
#pragma unroll
  for (int n = 0; n < 4; ++n) {
    int cc = cbase + n * 16;
    float bv = bias[cc];
#pragma unroll
    for (int m = 0; m < 4; ++m) {
#pragma unroll
      for (int j = 0; j < 4; ++j) {
        int r = rbase + m * 16 + j;
        if (r < NNODES) {
          float v = acc[m][n][j] + bv;
          v = fmaxf(v, 0.f);
          out[(size_t)r * DDIM + cc] = f2b(v);
        }
      }
    }
  }
}

// ---------------- pool + classifier (parallel) ----------------

// per-graph node counts via binary search on sorted batch
__global__ void k_cnt(const int* __restrict__ batch, int* __restrict__ cnt) {
  int g = threadIdx.x;
  if (g >= NGRAPH) return;
  int lo = 0, hi = NNODES;
  while (lo < hi) { int m = (lo + hi) >> 1; if (batch[m] < g) lo = m + 1; else hi = m; }
  int lo2 = lo, hi2 = NNODES;
  while (lo2 < hi2) { int m = (lo2 + hi2) >> 1; if (batch[m] < g + 1) lo2 = m + 1; else hi2 = m; }
  cnt[g] = lo2 - lo;
}

// 1024 waves; each wave owns a contiguous row range, accumulates full 256-col
// rows in registers (ushort4/lane), flushes to gsum on graph transition.
#define GSUM_WAVES 1024
__global__ void k_gsum(const unsigned short* __restrict__ h2,
                       const int* __restrict__ batch,
                       float* __restrict__ gsum) {  // [NGRAPH][DDIM], pre-zeroed
  int wave = (blockIdx.x * blockDim.x + threadIdx.x) >> 6;
  int lane = threadIdx.x & 63;
  const int per = (NNODES + GSUM_WAVES - 1) / GSUM_WAVES;
  int r0 = wave * per;
  int r1 = r0 + per; if (r1 > NNODES) r1 = NNODES;
  if (r0 >= r1) return;
  float a0 = 0.f, a1 = 0.f, a2 = 0.f, a3 = 0.f;
  int cur = batch[r0];
  for (int r = r0; r < r1; ++r) {
    int g = batch[r];
    if (g != cur) {
      float* gp = gsum + cur * DDIM + lane * 4;
      atomicAdd(gp + 0, a0); atomicAdd(gp + 1, a1);
      atomicAdd(gp + 2, a2); atomicAdd(gp + 3, a3);
      a0 = a1 = a2 = a3 = 0.f;
      cur = g;
    }
    ushort4 v = *(const ushort4*)(h2 + (size_t)r * DDIM + lane * 4);
    a0 += b2f(v.x); a1 += b2f(v.y); a2 += b2f(v.z); a3 += b2f(v.w);
  }
  float* gp = gsum + cur * DDIM + lane * 4;
  atomicAdd(gp + 0, a0); atomicAdd(gp + 1, a1);
  atomicAdd(gp + 2, a2); atomicAdd(gp + 3, a3);
}

// one block per graph: mean, then 256x32 matvec
__global__ void k_cls(const float* __restrict__ gsum, const int* __restrict__ cnt,
                      const float* __restrict__ Wc, const float* __restrict__ bc,
                      float* __restrict__ out) {
  int g = blockIdx.x;
  __shared__ float colmean[DDIM];
  int c = threadIdx.x;
  int n = cnt[g];
  float inv = (n > 0) ? 1.f / (float)n : 0.f;
  colmean[c] = gsum[g * DDIM + c] * inv;
  __syncthreads();
  if (c < NCLS) {
    float o = bc[c];
#pragma unroll 4
    for (int k = 0; k < DDIM; ++k) o += colmean[k] * Wc[k * NCLS + c];
    out[g * NCLS + c] = o;
  }
}

// ---------------- launch ----------------

extern "C" void kernel_launch(void* const* d_in, const int* in_sizes, int n_in,
                              void* d_out, int out_size, void* d_ws, size_t ws_size,
                              hipStream_t stream) {
  const float* x    = (const float*)d_in[0];
  const int* eidx   = (const int*)d_in[1];
  const int* batch  = (const int*)d_in[2];
  const float* W1l  = (const float*)d_in[3];
  const float* b1   = (const float*)d_in[4];
  const float* W1r  = (const float*)d_in[5];
  const float* W2l  = (const float*)d_in[6];
  const float* b2   = (const float*)d_in[7];
  const float* W2r  = (const float*)d_in[8];
  const float* Wc   = (const float*)d_in[9];
  const float* bc   = (const float*)d_in[10];
  float* out = (float*)d_out;

  const int* esrc = eidx;
  const int* edst = eidx + NEDGES;

  char* w = (char*)d_ws;
  size_t off = 0;
  auto alloc = [&](size_t bytes) -> char* {
    char* p = w + off;
    off = (off + bytes + 255) & ~(size_t)255;
    return p;
  };
  int* rowptr = (int*)alloc((NNODES + 1) * sizeof(int));
  int* cursor = (int*)alloc(NNODES * sizeof(int));   // also the histogram buffer
  int* col    = (int*)alloc(NEDGES * sizeof(int));
  unsigned short* xb   = (unsigned short*)alloc((size_t)NNODES * DDIM * 2);  // later reused for h2
  unsigned short* h1b  = (unsigned short*)alloc((size_t)NNODES * DDIM * 2);
  unsigned short* aggb = (unsigned short*)alloc((size_t)NNODES * DDIM * 2);
  unsigned short* WT1  = (unsigned short*)alloc(512 * 256 * 2);
  unsigned short* WT2  = (unsigned short*)alloc(512 * 256 * 2);
  float* gsum = (float*)alloc(NGRAPH * DDIM * sizeof(float));
  int* gcnt   = (int*)alloc(NGRAPH * sizeof(int));

  // CSR build
  hipMemsetAsync(cursor, 0, NNODES * sizeof(int), stream);
  k_hist<<<(NEDGES + 255) / 256, 256, 0, stream>>>(edst, cursor);
  k_scan<<<1, 1024, 0, stream>>>(cursor, rowptr, cursor);
  k_fill<<<(NEDGES + 255) / 256, 256, 0, stream>>>(esrc, edst, cursor, col);

  // conversions
  k_cvt_x<<<(NNODES * DDIM / 4 + 255) / 256, 256, 0, stream>>>(x, xb);
  k_cvt_w<<<(2 * 256 * 512 + 255) / 256, 256, 0, stream>>>(W1l, W1r, W2l, W2r, WT1, WT2);

  dim3 ggrid((NNODES + 127) / 128, 2);

  // layer 1
  k_agg<<<(NNODES + 3) / 4, 256, 0, stream>>>(xb, rowptr, col, aggb);
  k_gemm<<<ggrid, 256, 0, stream>>>(aggb, xb, WT1, b1, h1b);

  // layer 2 (h2 -> xb, reusing the buffer)
  k_agg<<<(NNODES + 3) / 4, 256, 0, stream>>>(h1b, rowptr, col, aggb);
  k_gemm<<<ggrid, 256, 0, stream>>>(aggb, h1b, WT2, b2, xb);

  // pool + classifier
  hipMemsetAsync(gsum, 0, NGRAPH * DDIM * sizeof(float), stream);
  k_cnt<<<1, 64, 0, stream>>>(batch, gcnt);
  k_gsum<<<GSUM_WAVES / 4, 256, 0, stream>>>(xb, batch, gsum);
  k_cls<<<NGRAPH, 256, 0, stream>>>(gsum, gcnt, Wc, bc, out);
}